// Round 1
// baseline (2251.761 us; speedup 1.0000x reference)
//
#include <hip/hip_runtime.h>
#include <cstddef>

#define BB    16
#define CDIM  512
#define HWN   784
#define KC    2048
#define NR    (BB*HWN)                  // 12544 rows
#define ETOT  ((size_t)BB*CDIM*HWN)     // 6422528 elements per tensor

// ---------------------------------------------------------------- utilities

__global__ void zero_acc(float* lacc) {
    if (threadIdx.x < 3) lacc[threadIdx.x] = 0.f;
}

// head (B,C,HW) -> f (N=B*HW, C) contiguous rows
__global__ __launch_bounds__(256)
void transpose_head(const float* __restrict__ head, float* __restrict__ f) {
    __shared__ float tile[32][33];
    int b = blockIdx.z, c0 = blockIdx.y * 32, h0 = blockIdx.x * 32;
    int t = threadIdx.x;
    const float* src = head + (size_t)b * CDIM * HWN;
    {
        int hl = t & 31, cl0 = t >> 5;
#pragma unroll
        for (int it = 0; it < 4; ++it) {
            int cl = cl0 + it * 8;
            int hw = h0 + hl;
            if (hw < HWN) tile[cl][hl] = src[(size_t)(c0 + cl) * HWN + hw];
        }
    }
    __syncthreads();
    float* dst = f + (size_t)b * HWN * CDIM;
    {
        int cl = t & 31, hl0 = t >> 5;
#pragma unroll
        for (int it = 0; it < 4; ++it) {
            int hl = hl0 + it * 8;
            int hw = h0 + hl;
            if (hw < HWN) dst[(size_t)hw * CDIM + c0 + cl] = tile[cl][hl];
        }
    }
}

// ||code_k||^2 for all 3 codebooks; grid (2048, 3), block 64
__global__ void code_norms(const float* __restrict__ c1, const float* __restrict__ c2,
                           const float* __restrict__ c3, float* __restrict__ cnorm) {
    int k = blockIdx.x;
    int cb = blockIdx.y;
    const float* cp = (cb == 0) ? c1 : (cb == 1) ? c2 : c3;
    int t = threadIdx.x;
    float s = 0.f;
#pragma unroll
    for (int i = 0; i < 8; ++i) {
        float v = cp[(size_t)k * CDIM + t + i * 64];
        s += v * v;
    }
#pragma unroll
    for (int off = 32; off; off >>= 1) s += __shfl_down(s, off);
    if (t == 0) cnorm[cb * KC + k] = s;
}

// ------------------------------------------------------------- argmin GEMM
// grid (196 row-tiles, 4 code-splits), block 256.
// Block: 64 rows x 512 codes (8 code tiles of 64). Thread (tr=t>>4, tc=t&15):
// rows 4*tr+i, codes ct + tc + 16*j  (bank-conflict-free B reads).
__global__ __launch_bounds__(256)
void argmin_partial(const float* __restrict__ f, const float* __restrict__ code,
                    const float* __restrict__ cnorm,
                    float* __restrict__ pval, int* __restrict__ pidx) {
    __shared__ float As[64][20];
    __shared__ float Bs[64][20];
    __shared__ float rv[64][16];
    __shared__ int   ri[64][16];

    int t = threadIdx.x;
    int tc = t & 15, tr = t >> 4;
    int rb = blockIdx.x * 64;
    int sp = blockIdx.y;            // code split 0..3
    int kb = sp * 512;

    float bestv[4] = {3.0e38f, 3.0e38f, 3.0e38f, 3.0e38f};
    int   besti[4] = {0, 0, 0, 0};

    int lrow = t >> 2;              // staging: row 0..63
    int lq   = (t & 3) * 4;         // staging: float4 slot

    for (int ct = 0; ct < 512; ct += 64) {
        float acc[4][4];
#pragma unroll
        for (int i = 0; i < 4; ++i)
#pragma unroll
            for (int j = 0; j < 4; ++j) acc[i][j] = 0.f;

        for (int cc = 0; cc < CDIM; cc += 16) {
            *(float4*)&As[lrow][lq] =
                *(const float4*)&f[(size_t)(rb + lrow) * CDIM + cc + lq];
            *(float4*)&Bs[lrow][lq] =
                *(const float4*)&code[(size_t)(kb + ct + lrow) * CDIM + cc + lq];
            __syncthreads();
#pragma unroll
            for (int q = 0; q < 4; ++q) {
                float4 a[4], bf[4];
#pragma unroll
                for (int i = 0; i < 4; ++i) a[i]  = *(float4*)&As[tr * 4 + i][q * 4];
#pragma unroll
                for (int j = 0; j < 4; ++j) bf[j] = *(float4*)&Bs[tc + 16 * j][q * 4];
#pragma unroll
                for (int i = 0; i < 4; ++i)
#pragma unroll
                    for (int j = 0; j < 4; ++j)
                        acc[i][j] += a[i].x * bf[j].x + a[i].y * bf[j].y +
                                     a[i].z * bf[j].z + a[i].w * bf[j].w;
            }
            __syncthreads();
        }
        // dist = ||c||^2 - 2 f.c ; update running min (k ascending in j)
#pragma unroll
        for (int j = 0; j < 4; ++j) {
            int k = kb + ct + tc + 16 * j;
            float cn = cnorm[k];
#pragma unroll
            for (int i = 0; i < 4; ++i) {
                float d = fmaf(-2.0f, acc[i][j], cn);
                if (d < bestv[i]) { bestv[i] = d; besti[i] = k; }
            }
        }
    }
    // cross-thread reduce per row (16 tc entries), lower index wins ties
#pragma unroll
    for (int i = 0; i < 4; ++i) {
        rv[tr * 4 + i][tc] = bestv[i];
        ri[tr * 4 + i][tc] = besti[i];
    }
    __syncthreads();
    if (t < 64) {
        float bv = rv[t][0]; int bi = ri[t][0];
#pragma unroll
        for (int c2 = 1; c2 < 16; ++c2) {
            float v = rv[t][c2]; int ii = ri[t][c2];
            if (v < bv || (v == bv && ii < bi)) { bv = v; bi = ii; }
        }
        pval[(size_t)sp * NR + rb + t] = bv;
        pidx[(size_t)sp * NR + rb + t] = bi;
    }
}

__global__ void combine_idx(const float* __restrict__ pval, const int* __restrict__ pidx,
                            int* __restrict__ idx) {
    int n = blockIdx.x * 256 + threadIdx.x;
    if (n >= NR) return;
    float bv = pval[n]; int bi = pidx[n];
#pragma unroll
    for (int s = 1; s < 4; ++s) {
        float v = pval[(size_t)s * NR + n]; int ii = pidx[(size_t)s * NR + n];
        if (v < bv || (v == bv && ii < bi)) { bv = v; bi = ii; }
    }
    idx[n] = bi;
}

// ------------------------------------------------------------ update stage
// grid (25 hw-tiles, 16 c-tiles, 16 b), block 256.
// Reads f (n,c), gathers q, residual in place, writes x_s (b,c,hw) via LDS
// transpose, optional recon, block-reduced loss atomicAdd.
__global__ __launch_bounds__(256)
void vq_update(float* __restrict__ f, const float* __restrict__ code,
               const int* __restrict__ idx, float* __restrict__ xout,
               const float* __restrict__ x1p, const float* __restrict__ x2p,
               float* __restrict__ reconp, float* __restrict__ lacc) {
    __shared__ float qt[32][33];
    __shared__ float wsum[4];
    int b = blockIdx.z, c0 = blockIdx.y * 32, h0 = blockIdx.x * 32;
    int t = threadIdx.x;
    int tx = t & 31, ty0 = t >> 5;
    float lsum = 0.f;
#pragma unroll
    for (int it = 0; it < 4; ++it) {
        int hwl = ty0 + it * 8;
        int hw = h0 + hwl;
        float qv = 0.f;
        if (hw < HWN) {
            int n = b * HWN + hw;
            size_t fo = (size_t)n * CDIM + c0 + tx;
            float fv = f[fo];
            qv = code[(size_t)idx[n] * CDIM + c0 + tx];
            float rem = fv - qv;
            f[fo] = rem;
            lsum += rem * rem;
        }
        qt[tx][hwl] = qv;
    }
    __syncthreads();
    {
        int hl = t & 31, cl0 = t >> 5;
#pragma unroll
        for (int it = 0; it < 4; ++it) {
            int cl = cl0 + it * 8;
            int hw = h0 + hl;
            if (hw < HWN) {
                size_t off = ((size_t)b * CDIM + c0 + cl) * HWN + hw;
                float qv = qt[cl][hl];
                xout[off] = qv;
                if (reconp) reconp[off] = qv + x1p[off] + x2p[off];
            }
        }
    }
    // loss reduction: 4 waves -> LDS -> one atomic per block
#pragma unroll
    for (int off = 32; off; off >>= 1) lsum += __shfl_down(lsum, off);
    int lane = t & 63, w = t >> 6;
    if (lane == 0) wsum[w] = lsum;
    __syncthreads();
    if (t == 0) atomicAdd(lacc, wsum[0] + wsum[1] + wsum[2] + wsum[3]);
}

__global__ void finalize_losses(const float* __restrict__ lacc, float* __restrict__ out) {
    int t = threadIdx.x;
    if (t < 3) out[t] = 2.0f * lacc[t] / (float)ETOT;
}

// ------------------------------------------------------------------- launch

extern "C" void kernel_launch(void* const* d_in, const int* in_sizes, int n_in,
                              void* d_out, int out_size, void* d_ws, size_t ws_size,
                              hipStream_t stream) {
    (void)in_sizes; (void)n_in; (void)out_size; (void)ws_size;
    const float* head = (const float*)d_in[0];
    const float* cbs[3] = {(const float*)d_in[1], (const float*)d_in[2], (const float*)d_in[3]};
    float* out = (float*)d_out;

    char* ws = (char*)d_ws;
    float* f     = (float*)ws;                 size_t off = ETOT * 4;
    float* pval  = (float*)(ws + off);         off += (size_t)NR * 4 * 4;
    int*   pidx  = (int*)(ws + off);           off += (size_t)NR * 4 * 4;
    int*   idx   = (int*)(ws + off);           off += (size_t)NR * 4;
    float* cnorm = (float*)(ws + off);         off += (size_t)3 * KC * 4;
    float* lacc  = (float*)(ws + off);         off += 3 * 4;

    zero_acc<<<1, 64, 0, stream>>>(lacc);
    transpose_head<<<dim3(25, 16, 16), 256, 0, stream>>>(head, f);
    code_norms<<<dim3(KC, 3), 64, 0, stream>>>(cbs[0], cbs[1], cbs[2], cnorm);

    for (int s = 0; s < 3; ++s) {
        argmin_partial<<<dim3(196, 4), 256, 0, stream>>>(f, cbs[s], cnorm + (size_t)s * KC,
                                                         pval, pidx);
        combine_idx<<<dim3((NR + 255) / 256), 256, 0, stream>>>(pval, pidx, idx);
        float* xout   = out + (size_t)s * ETOT;
        float* reconp = (s == 2) ? out + 3 * ETOT + 3 : nullptr;
        vq_update<<<dim3(25, 16, 16), 256, 0, stream>>>(f, cbs[s], idx, xout,
                                                        out, out + ETOT, reconp,
                                                        lacc + s);
    }
    finalize_losses<<<1, 64, 0, stream>>>(lacc, out + 3 * ETOT);
}

// Round 5
// 1129.089 us; speedup vs baseline: 1.9943x; 1.9943x over previous
//
#include <hip/hip_runtime.h>
#include <cstddef>

#define BB    16
#define CDIM  512
#define HWN   784
#define KC    2048
#define NR    (BB*HWN)                  // 12544 rows (= 98*128)
#define ETOT  ((size_t)BB*CDIM*HWN)     // 6422528 elements per tensor
#define NSPL  2                         // code splits (1024 codes per block)
#define NT8   8                         // 128-code tiles per split
#define TAU   0.02f
#define LSTR  40                        // LDS row stride (halves)
#define LOSC  2048.0f                   // lo-plane scale (2^11)
#define ILOSC 4.8828125e-4f             // 1/2048

typedef _Float16 hf8 __attribute__((ext_vector_type(8)));
typedef float f32x4 __attribute__((ext_vector_type(4)));

// 16 floats -> f16 hi plane + f16 lo plane (scaled by 2^11; no denormals)
__device__ __forceinline__ void cvt16h(const float4* v, hf8* hi, hf8* lo) {
#pragma unroll
    for (int i = 0; i < 4; ++i) {
        float x0 = v[i].x, x1 = v[i].y, x2 = v[i].z, x3 = v[i].w;
        _Float16 h0 = (_Float16)x0, h1 = (_Float16)x1;
        _Float16 h2 = (_Float16)x2, h3 = (_Float16)x3;
        _Float16 l0 = (_Float16)((x0 - (float)h0) * LOSC);
        _Float16 l1 = (_Float16)((x1 - (float)h1) * LOSC);
        _Float16 l2 = (_Float16)((x2 - (float)h2) * LOSC);
        _Float16 l3 = (_Float16)((x3 - (float)h3) * LOSC);
        int w = i >> 1, e = (i & 1) * 4;
        hi[w][e + 0] = h0; hi[w][e + 1] = h1; hi[w][e + 2] = h2; hi[w][e + 3] = h3;
        lo[w][e + 0] = l0; lo[w][e + 1] = l1; lo[w][e + 2] = l2; lo[w][e + 3] = l3;
    }
}

// ---------------------------------------------------------------- utilities

__global__ void zero_acc(float* lacc) {
    if (threadIdx.x < 3) lacc[threadIdx.x] = 0.f;
}

// head (B,C,HW) -> f (N=B*HW, C) contiguous rows
__global__ __launch_bounds__(256)
void transpose_head(const float* __restrict__ head, float* __restrict__ f) {
    __shared__ float tile[32][33];
    int b = blockIdx.z, c0 = blockIdx.y * 32, h0 = blockIdx.x * 32;
    int t = threadIdx.x;
    const float* src = head + (size_t)b * CDIM * HWN;
    {
        int hl = t & 31, cl0 = t >> 5;
#pragma unroll
        for (int it = 0; it < 4; ++it) {
            int cl = cl0 + it * 8;
            int hw = h0 + hl;
            if (hw < HWN) tile[cl][hl] = src[(size_t)(c0 + cl) * HWN + hw];
        }
    }
    __syncthreads();
    float* dst = f + (size_t)b * HWN * CDIM;
    {
        int cl = t & 31, hl0 = t >> 5;
#pragma unroll
        for (int it = 0; it < 4; ++it) {
            int hl = hl0 + it * 8;
            int hw = h0 + hl;
            if (hw < HWN) dst[(size_t)hw * CDIM + c0 + cl] = tile[cl][hl];
        }
    }
}

// ||code_k||^2 fp32 for ONE codebook; grid 2048, block 64
__global__ void code_norms1(const float* __restrict__ cp, float* __restrict__ cnorm) {
    int k = blockIdx.x;
    int t = threadIdx.x;
    float s = 0.f;
#pragma unroll
    for (int i = 0; i < 8; ++i) {
        float v = cp[(size_t)k * CDIM + t + i * 64];
        s += v * v;
    }
#pragma unroll
    for (int off = 32; off; off >>= 1) s += __shfl_down(s, off);
    if (t == 0) cnorm[k] = s;
}

// ------------------------------------------------------------- MFMA argmin
// grid (2 code-splits, 98 row-tiles), block 256 (4 waves, 2x2 of 64x64).
// fp16 2-plane (hi + 2^11-scaled lo): dot = acch + accl/2048, where
// accl = f_hi*c_lo' + f_lo'*c_hi. Per-lane running top-2 across tiles.
// RACE FIX vs R2-R4: waves (wr,0) and (wr,1) share rows -> per-wave results
// go to LDS msm[row][wc]; merged by one thread per row after a barrier.
__global__ __launch_bounds__(256)
void argmin_mfma(const float* __restrict__ f, const float* __restrict__ code,
                 const float* __restrict__ cnorm, float4* __restrict__ part) {
    __shared__ _Float16 A1[128 * LSTR];
    __shared__ _Float16 A2[128 * LSTR];
    __shared__ _Float16 B1[128 * LSTR];
    __shared__ _Float16 B2[128 * LSTR];
    __shared__ float4 msm[128][2];

    int t = threadIdx.x;
    int lane = t & 63, wid = t >> 6;
    int wr = wid >> 1, wc = wid & 1;
    int sp = blockIdx.x;                     // 0..1
    int rb = blockIdx.y * 128;
    int kb = sp * 1024;

    // staging: thread t owns row t>>1, float quarter [(t&1)*16, +16) per chunk
    int srow = t >> 1, sq = (t & 1) * 16;
    const float* gA = f    + (size_t)(rb + srow) * CDIM + sq;
    const float* gB = code + (size_t)(kb + srow) * CDIM + sq;
    int lws = srow * LSTR + sq;

    int rA = (wr * 64 + (lane & 15)) * LSTR + (lane >> 4) * 8;
    int rB = (wc * 64 + (lane & 15)) * LSTR + (lane >> 4) * 8;

    float bv1[4][4], bv2[4][4];
    int   bi1[4][4], bi2[4][4];
#pragma unroll
    for (int m = 0; m < 4; ++m)
#pragma unroll
        for (int i = 0; i < 4; ++i) {
            bv1[m][i] = 3.0e38f; bv2[m][i] = 3.0e38f;
            bi1[m][i] = 0x7fffffff; bi2[m][i] = 0x7fffffff;
        }

    for (int ct = 0; ct < NT8; ++ct) {
        f32x4 acch[4][4], accl[4][4];
#pragma unroll
        for (int m = 0; m < 4; ++m)
#pragma unroll
            for (int n = 0; n < 4; ++n) { acch[m][n] = (f32x4)0.f; accl[m][n] = (f32x4)0.f; }

        for (int cc = 0; cc < 16; ++cc) {
            float4 va[4], vb[4];
            const float* pa = gA + cc * 32;
            const float* pb = gB + (size_t)ct * 128 * CDIM + cc * 32;
#pragma unroll
            for (int i = 0; i < 4; ++i) {
                va[i] = *(const float4*)(pa + i * 4);
                vb[i] = *(const float4*)(pb + i * 4);
            }
            hf8 ha1[2], ha2[2], hb1[2], hb2[2];
            cvt16h(va, ha1, ha2);
            cvt16h(vb, hb1, hb2);

            __syncthreads();                 // prev iter's ds_reads complete
            *(hf8*)&A1[lws] = ha1[0]; *(hf8*)&A1[lws + 8] = ha1[1];
            *(hf8*)&A2[lws] = ha2[0]; *(hf8*)&A2[lws + 8] = ha2[1];
            *(hf8*)&B1[lws] = hb1[0]; *(hf8*)&B1[lws + 8] = hb1[1];
            *(hf8*)&B2[lws] = hb2[0]; *(hf8*)&B2[lws + 8] = hb2[1];
            __syncthreads();

            hf8 b1[4], b2[4];
#pragma unroll
            for (int n = 0; n < 4; ++n) {
                b1[n] = *(hf8*)&B1[rB + n * 16 * LSTR];
                b2[n] = *(hf8*)&B2[rB + n * 16 * LSTR];
            }
#pragma unroll
            for (int m = 0; m < 4; ++m) {
                hf8 am1 = *(hf8*)&A1[rA + m * 16 * LSTR];
                hf8 am2 = *(hf8*)&A2[rA + m * 16 * LSTR];
#pragma unroll
                for (int n = 0; n < 4; ++n) {
                    acch[m][n] = __builtin_amdgcn_mfma_f32_16x16x32_f16(am1, b1[n], acch[m][n], 0, 0, 0);
                    accl[m][n] = __builtin_amdgcn_mfma_f32_16x16x32_f16(am1, b2[n], accl[m][n], 0, 0, 0);
                    accl[m][n] = __builtin_amdgcn_mfma_f32_16x16x32_f16(am2, b1[n], accl[m][n], 0, 0, 0);
                }
            }
        }

        // fold distances into per-lane running top-2
#pragma unroll
        for (int m = 0; m < 4; ++m)
#pragma unroll
            for (int i = 0; i < 4; ++i)
#pragma unroll
                for (int n = 0; n < 4; ++n) {
                    int kcode = kb + ct * 128 + wc * 64 + n * 16 + (lane & 15);
                    float dot = acch[m][n][i] + accl[m][n][i] * ILOSC;
                    float d = fmaf(-2.f, dot, cnorm[kcode]);
                    if (d < bv1[m][i]) {
                        bv2[m][i] = bv1[m][i]; bi2[m][i] = bi1[m][i];
                        bv1[m][i] = d;         bi1[m][i] = kcode;
                    } else if (d < bv2[m][i]) {
                        bv2[m][i] = d; bi2[m][i] = kcode;
                    }
                }
    }

    // in-wave butterfly over the 16 cols, then deposit per (row, wc) into LDS
    int g = lane >> 4;
#pragma unroll
    for (int m = 0; m < 4; ++m)
#pragma unroll
        for (int i = 0; i < 4; ++i) {
            float v1 = bv1[m][i], v2 = bv2[m][i];
            int   i1 = bi1[m][i], i2 = bi2[m][i];
#pragma unroll
            for (int off = 1; off < 16; off <<= 1) {
                float ov1 = __shfl_xor(v1, off, 64); int oi1 = __shfl_xor(i1, off, 64);
                float ov2 = __shfl_xor(v2, off, 64); int oi2 = __shfl_xor(i2, off, 64);
                if (ov1 < v1 || (ov1 == v1 && oi1 < i1)) {
                    float tv = v1; int ti = i1;
                    v1 = ov1; i1 = oi1; ov1 = tv; oi1 = ti;
                }
                if (ov1 < v2 || (ov1 == v2 && oi1 < i2)) { v2 = ov1; i2 = oi1; }
                if (ov2 < v2 || (ov2 == v2 && oi2 < i2)) { v2 = ov2; i2 = oi2; }
            }
            if ((lane & 15) == 0)
                msm[wr * 64 + m * 16 + g * 4 + i][wc] =
                    make_float4(v1, __int_as_float(i1), v2, __int_as_float(i2));
        }
    __syncthreads();

    // one thread per row merges the two wc halves (disjoint code sets)
    if (t < 128) {
        float4 q0 = msm[t][0], q1 = msm[t][1];
        float v1 = q0.x, v2 = q0.z;
        int   i1 = __float_as_int(q0.y), i2 = __float_as_int(q0.w);
        float ov1 = q1.x, ov2 = q1.z;
        int   oi1 = __float_as_int(q1.y), oi2 = __float_as_int(q1.w);
        if (ov1 < v1 || (ov1 == v1 && oi1 < i1)) {
            float tv = v1; int ti = i1;
            v1 = ov1; i1 = oi1; ov1 = tv; oi1 = ti;
        }
        if (ov1 < v2 || (ov1 == v2 && oi1 < i2)) { v2 = ov1; i2 = oi1; }
        if (ov2 < v2 || (ov2 == v2 && oi2 < i2)) { v2 = ov2; i2 = oi2; }
        part[(size_t)sp * NR + rb + t] =
            make_float4(v1, __int_as_float(i1), v2, __int_as_float(i2));
    }
}

// combine 2 partials per row; fp64 re-check when top-2 gap < TAU
__global__ __launch_bounds__(256)
void combine_fix(const float4* __restrict__ part, const float* __restrict__ f,
                 const float* __restrict__ code, int* __restrict__ idx) {
    int n = blockIdx.x * 256 + threadIdx.x;
    if (n >= NR) return;
    float bv1 = 3.0e38f, bv2 = 3.0e38f;
    int bi1 = 0x7fffffff, bi2 = 0x7fffffff;
#pragma unroll
    for (int p = 0; p < NSPL; ++p) {
        float4 q = part[(size_t)p * NR + n];
        float ov1 = q.x, ov2 = q.z;
        int oi1 = __float_as_int(q.y), oi2 = __float_as_int(q.w);
        if (ov1 < bv1 || (ov1 == bv1 && oi1 < bi1)) {
            float tv = bv1; int ti = bi1;
            bv1 = ov1; bi1 = oi1; ov1 = tv; oi1 = ti;
        }
        if (ov1 < bv2 || (ov1 == bv2 && oi1 < bi2)) { bv2 = ov1; bi2 = oi1; }
        if (ov2 < bv2 || (ov2 == bv2 && oi2 < bi2)) { bv2 = ov2; bi2 = oi2; }
    }
    bi1 = min(max(bi1, 0), KC - 1);
    bi2 = min(max(bi2, 0), KC - 1);
    if (bv2 - bv1 < TAU) {
        const float* fr = f + (size_t)n * CDIM;
        const float* ca = code + (size_t)bi1 * CDIM;
        const float* cb = code + (size_t)bi2 * CDIM;
        double d1 = 0.0, d2 = 0.0;
        for (int j = 0; j < CDIM; ++j) {
            double fv = fr[j], av = ca[j], bv = cb[j];
            d1 += av * av - 2.0 * fv * av;
            d2 += bv * bv - 2.0 * fv * bv;
        }
        if (d2 < d1 || (d2 == d1 && bi2 < bi1)) bi1 = bi2;
    }
    idx[n] = bi1;
}

// ------------------------------------------------------------ update stage
__global__ __launch_bounds__(256)
void vq_update(float* __restrict__ f, const float* __restrict__ code,
               const int* __restrict__ idx, float* __restrict__ xout,
               const float* __restrict__ x1p, const float* __restrict__ x2p,
               float* __restrict__ reconp, float* __restrict__ lacc) {
    __shared__ float qt[32][33];
    __shared__ float wsum[4];
    int b = blockIdx.z, c0 = blockIdx.y * 32, h0 = blockIdx.x * 32;
    int t = threadIdx.x;
    int tx = t & 31, ty0 = t >> 5;
    float lsum = 0.f;
#pragma unroll
    for (int it = 0; it < 4; ++it) {
        int hwl = ty0 + it * 8;
        int hw = h0 + hwl;
        float qv = 0.f;
        if (hw < HWN) {
            int n = b * HWN + hw;
            size_t fo = (size_t)n * CDIM + c0 + tx;
            float fv = f[fo];
            qv = code[(size_t)idx[n] * CDIM + c0 + tx];
            float rem = fv - qv;
            f[fo] = rem;
            lsum += rem * rem;
        }
        qt[tx][hwl] = qv;
    }
    __syncthreads();
    {
        int hl = t & 31, cl0 = t >> 5;
#pragma unroll
        for (int it = 0; it < 4; ++it) {
            int cl = cl0 + it * 8;
            int hw = h0 + hl;
            if (hw < HWN) {
                size_t off = ((size_t)b * CDIM + c0 + cl) * HWN + hw;
                float qv = qt[cl][hl];
                xout[off] = qv;
                if (reconp) reconp[off] = qv + x1p[off] + x2p[off];
            }
        }
    }
#pragma unroll
    for (int off = 32; off; off >>= 1) lsum += __shfl_down(lsum, off);
    int lane = t & 63, w = t >> 6;
    if (lane == 0) wsum[w] = lsum;
    __syncthreads();
    if (t == 0) atomicAdd(lacc, wsum[0] + wsum[1] + wsum[2] + wsum[3]);
}

__global__ void finalize_losses(const float* __restrict__ lacc, float* __restrict__ out) {
    int t = threadIdx.x;
    if (t < 3) out[t] = 2.0f * lacc[t] / (float)ETOT;
}

// ------------------------------------------------------------------- launch

extern "C" void kernel_launch(void* const* d_in, const int* in_sizes, int n_in,
                              void* d_out, int out_size, void* d_ws, size_t ws_size,
                              hipStream_t stream) {
    (void)in_sizes; (void)n_in; (void)out_size; (void)ws_size;
    const float* head = (const float*)d_in[0];
    const float* cbs[3] = {(const float*)d_in[1], (const float*)d_in[2], (const float*)d_in[3]};
    float* out = (float*)d_out;

    // ws layout kept STRICTLY within round-1's proven-valid 26,166,284 bytes
    char* ws = (char*)d_ws;
    float*  f     = (float*)ws;              size_t off = ETOT * 4;              // 25,690,112
    float4* part  = (float4*)(ws + off);     off += (size_t)NSPL * NR * 16;      // +401,408
    int*    idx   = (int*)(ws + off);        off += (size_t)NR * 4;              // +50,176
    float*  cnorm = (float*)(ws + off);      off += (size_t)KC * 4;              // +8,192
    float*  lacc  = (float*)(ws + off);      off += 16;                          // total 26,149,904

    zero_acc<<<1, 64, 0, stream>>>(lacc);
    transpose_head<<<dim3(25, 16, 16), 256, 0, stream>>>(head, f);

    for (int s = 0; s < 3; ++s) {
        code_norms1<<<dim3(KC), 64, 0, stream>>>(cbs[s], cnorm);
        argmin_mfma<<<dim3(NSPL, 98), 256, 0, stream>>>(f, cbs[s], cnorm, part);
        combine_fix<<<dim3((NR + 255) / 256), 256, 0, stream>>>(part, f, cbs[s], idx);
        float* xout   = out + (size_t)s * ETOT;
        float* reconp = (s == 2) ? out + 3 * ETOT + 3 : nullptr;
        vq_update<<<dim3(25, 16, 16), 256, 0, stream>>>(f, cbs[s], idx, xout,
                                                        out, out + ETOT, reconp,
                                                        lacc + s);
    }
    finalize_losses<<<1, 64, 0, stream>>>(lacc, out + 3 * ETOT);
}

// Round 6
// 878.417 us; speedup vs baseline: 2.5634x; 1.2854x over previous
//
#include <hip/hip_runtime.h>
#include <cstddef>

#define BB    16
#define CDIM  512
#define HWN   784
#define KC    2048
#define NR    (BB*HWN)                  // 12544 rows (= 98*128)
#define ETOT  ((size_t)BB*CDIM*HWN)     // 6422528 elements per tensor
#define NSTRIP 16                       // fast path: code strips of 128
#define NSPL  2                         // fallback: code splits (1024/block)
#define NT8   8
#define TAU   0.02f
#define LSTR  40                        // fallback LDS row stride (halves)
#define LOSC  2048.0f
#define ILOSC 4.8828125e-4f

typedef _Float16 hf8 __attribute__((ext_vector_type(8)));
typedef float f32x4 __attribute__((ext_vector_type(4)));

__device__ __forceinline__ void gload_lds16(const void* g, void* l) {
    __builtin_amdgcn_global_load_lds((const __attribute__((address_space(1))) void*)g,
                                     (__attribute__((address_space(3))) void*)l, 16, 0, 0);
}

// ---------------------------------------------------------------- utilities

__global__ void zero_acc(float* lacc) {
    if (threadIdx.x < 3) lacc[threadIdx.x] = 0.f;
}

__global__ __launch_bounds__(256)
void transpose_head(const float* __restrict__ head, float* __restrict__ f) {
    __shared__ float tile[32][33];
    int b = blockIdx.z, c0 = blockIdx.y * 32, h0 = blockIdx.x * 32;
    int t = threadIdx.x;
    const float* src = head + (size_t)b * CDIM * HWN;
    {
        int hl = t & 31, cl0 = t >> 5;
#pragma unroll
        for (int it = 0; it < 4; ++it) {
            int cl = cl0 + it * 8;
            int hw = h0 + hl;
            if (hw < HWN) tile[cl][hl] = src[(size_t)(c0 + cl) * HWN + hw];
        }
    }
    __syncthreads();
    float* dst = f + (size_t)b * HWN * CDIM;
    {
        int cl = t & 31, hl0 = t >> 5;
#pragma unroll
        for (int it = 0; it < 4; ++it) {
            int hl = hl0 + it * 8;
            int hw = h0 + hl;
            if (hw < HWN) dst[(size_t)hw * CDIM + c0 + cl] = tile[cl][hl];
        }
    }
}

__global__ void code_norms1(const float* __restrict__ cp, float* __restrict__ cnorm) {
    int k = blockIdx.x;
    int t = threadIdx.x;
    float s = 0.f;
#pragma unroll
    for (int i = 0; i < 8; ++i) {
        float v = cp[(size_t)k * CDIM + t + i * 64];
        s += v * v;
    }
#pragma unroll
    for (int off = 32; off; off >>= 1) s += __shfl_down(s, off);
    if (t == 0) cnorm[k] = s;
}

// --------------------------------------------------- fast path: split planes
// fp32 [R][512] -> f16 [R][1024]: hi plane [0,512), UNSCALED lo plane [512,1024)
__global__ __launch_bounds__(256)
void split_rows(const float* __restrict__ src, _Float16* __restrict__ dst, int nrow) {
    int tid = blockIdx.x * 256 + threadIdx.x;        // 8 elems per thread
    int row = tid >> 6, c8 = (tid & 63) * 8;
    if (row >= nrow) return;
    const float* p = src + (size_t)row * CDIM + c8;
    float4 v0 = *(const float4*)p, v1 = *(const float4*)(p + 4);
    hf8 hi, lo;
    float x[8] = {v0.x, v0.y, v0.z, v0.w, v1.x, v1.y, v1.z, v1.w};
#pragma unroll
    for (int j = 0; j < 8; ++j) {
        _Float16 h = (_Float16)x[j];
        hi[j] = h;
        lo[j] = (_Float16)(x[j] - (float)h);
    }
    *(hf8*)&dst[(size_t)row * 1024 + c8] = hi;
    *(hf8*)&dst[(size_t)row * 1024 + 512 + c8] = lo;
}

// --------------------------------------------------- fast path: MFMA argmin
// grid (16 strips, 98 row tiles), block 256 (4 waves, 2x2 of 64x64).
// global_load_lds width-16 staging, source-swizzled (slot ^= (row>>1)&3),
// swizzled ds_read_b128 (2-way = free). Single fp32 acc per (m,n):
// dot = hi*chi + hi*clo + lo*chi  (lo*clo ~ 1e-7, dropped; TAU recheck covers).
__global__ __launch_bounds__(256)
void argmin_fast(const _Float16* __restrict__ fs, const _Float16* __restrict__ cs,
                 const float* __restrict__ cnorm, float4* __restrict__ part) {
    __shared__ _Float16 Ah[128 * 32];
    __shared__ _Float16 Al[128 * 32];
    __shared__ _Float16 Bh[128 * 32];
    __shared__ _Float16 Bl[128 * 32];
    __shared__ float4 msm[128][2];

    int t = threadIdx.x;
    int lane = t & 63, w = t >> 6;
    int wr = w >> 1, wc = w & 1;
    int rb = blockIdx.y * 128, cb = blockIdx.x * 128;

    // staging: thread t owns LDS granules t and 256+t (16B each, linear)
    int r1 = t >> 2, s1 = t & 3;
    int sg1 = s1 ^ ((r1 >> 1) & 3);
    int r2 = 64 + r1;
    int sg2 = s1 ^ ((r2 >> 1) & 3);
    const _Float16* gA1 = fs + (size_t)(rb + r1) * 1024 + sg1 * 8;
    const _Float16* gA2 = fs + (size_t)(rb + r2) * 1024 + sg2 * 8;
    const _Float16* gB1 = cs + (size_t)(cb + r1) * 1024 + sg1 * 8;
    const _Float16* gB2 = cs + (size_t)(cb + r2) * 1024 + sg2 * 8;
    _Float16* lA1 = &Ah[(size_t)t * 8];
    _Float16* lA2 = &Ah[(size_t)(256 + t) * 8];
    _Float16* lB1 = &Bh[(size_t)t * 8];
    _Float16* lB2 = &Bh[(size_t)(256 + t) * 8];
    _Float16* lA1l = &Al[(size_t)t * 8];
    _Float16* lA2l = &Al[(size_t)(256 + t) * 8];
    _Float16* lB1l = &Bl[(size_t)t * 8];
    _Float16* lB2l = &Bl[(size_t)(256 + t) * 8];

    // fragment read addressing (swizzle term constant across m/n since 16-row
    // steps leave (row>>1)&3 unchanged)
    int frA = wr * 64 + (lane & 15);
    int frB = wc * 64 + (lane & 15);
    int fslot = lane >> 4;
    int sA = fslot ^ ((frA >> 1) & 3);
    int sB = fslot ^ ((frB >> 1) & 3);
    int oA = frA * 32 + sA * 8;
    int oB = frB * 32 + sB * 8;

    f32x4 acc[4][4];
#pragma unroll
    for (int m = 0; m < 4; ++m)
#pragma unroll
        for (int n = 0; n < 4; ++n) acc[m][n] = (f32x4)0.f;

    for (int kk = 0; kk < 16; ++kk) {
        int ko = kk * 32;
        gload_lds16(gA1 + ko, lA1);        gload_lds16(gA2 + ko, lA2);
        gload_lds16(gA1 + ko + 512, lA1l); gload_lds16(gA2 + ko + 512, lA2l);
        gload_lds16(gB1 + ko, lB1);        gload_lds16(gB2 + ko, lB2);
        gload_lds16(gB1 + ko + 512, lB1l); gload_lds16(gB2 + ko + 512, lB2l);
        __syncthreads();                   // drains vmcnt: LDS tiles ready
        hf8 bh[4], bl[4];
#pragma unroll
        for (int n = 0; n < 4; ++n) {
            bh[n] = *(hf8*)&Bh[oB + n * 16 * 32];
            bl[n] = *(hf8*)&Bl[oB + n * 16 * 32];
        }
#pragma unroll
        for (int m = 0; m < 4; ++m) {
            hf8 ah = *(hf8*)&Ah[oA + m * 16 * 32];
            hf8 al = *(hf8*)&Al[oA + m * 16 * 32];
#pragma unroll
            for (int n = 0; n < 4; ++n) {
                acc[m][n] = __builtin_amdgcn_mfma_f32_16x16x32_f16(ah, bh[n], acc[m][n], 0, 0, 0);
                acc[m][n] = __builtin_amdgcn_mfma_f32_16x16x32_f16(ah, bl[n], acc[m][n], 0, 0, 0);
                acc[m][n] = __builtin_amdgcn_mfma_f32_16x16x32_f16(al, bh[n], acc[m][n], 0, 0, 0);
            }
        }
        __syncthreads();                   // reads done before next DMA write
    }

    // per-lane top-2 over n, butterfly over the 16 cols, deposit per (row,wc)
    int g = lane >> 4;
#pragma unroll
    for (int m = 0; m < 4; ++m)
#pragma unroll
        for (int i = 0; i < 4; ++i) {
            float v1 = 3.0e38f, v2 = 3.0e38f;
            int i1 = 0x7fffffff, i2 = 0x7fffffff;
#pragma unroll
            for (int n = 0; n < 4; ++n) {
                int kcode = cb + wc * 64 + n * 16 + (lane & 15);
                float d = fmaf(-2.f, acc[m][n][i], cnorm[kcode]);
                if (d < v1) { v2 = v1; i2 = i1; v1 = d; i1 = kcode; }
                else if (d < v2) { v2 = d; i2 = kcode; }
            }
#pragma unroll
            for (int off = 1; off < 16; off <<= 1) {
                float ov1 = __shfl_xor(v1, off, 64); int oi1 = __shfl_xor(i1, off, 64);
                float ov2 = __shfl_xor(v2, off, 64); int oi2 = __shfl_xor(i2, off, 64);
                if (ov1 < v1 || (ov1 == v1 && oi1 < i1)) {
                    float tv = v1; int ti = i1;
                    v1 = ov1; i1 = oi1; ov1 = tv; oi1 = ti;
                }
                if (ov1 < v2 || (ov1 == v2 && oi1 < i2)) { v2 = ov1; i2 = oi1; }
                if (ov2 < v2 || (ov2 == v2 && oi2 < i2)) { v2 = ov2; i2 = oi2; }
            }
            if ((lane & 15) == 0)
                msm[wr * 64 + m * 16 + g * 4 + i][wc] =
                    make_float4(v1, __int_as_float(i1), v2, __int_as_float(i2));
        }
    __syncthreads();
    if (t < 128) {
        float4 q0 = msm[t][0], q1 = msm[t][1];
        float v1 = q0.x, v2 = q0.z;
        int   i1 = __float_as_int(q0.y), i2 = __float_as_int(q0.w);
        float ov1 = q1.x, ov2 = q1.z;
        int   oi1 = __float_as_int(q1.y), oi2 = __float_as_int(q1.w);
        if (ov1 < v1 || (ov1 == v1 && oi1 < i1)) {
            float tv = v1; int ti = i1;
            v1 = ov1; i1 = oi1; ov1 = tv; oi1 = ti;
        }
        if (ov1 < v2 || (ov1 == v2 && oi1 < i2)) { v2 = ov1; i2 = oi1; }
        if (ov2 < v2 || (ov2 == v2 && oi2 < i2)) { v2 = ov2; i2 = oi2; }
        part[(size_t)blockIdx.x * NR + rb + t] =
            make_float4(v1, __int_as_float(i1), v2, __int_as_float(i2));
    }
}

// ----------------------------------------------- fallback MFMA argmin (R5)
__device__ __forceinline__ void cvt16h(const float4* v, hf8* hi, hf8* lo) {
#pragma unroll
    for (int i = 0; i < 4; ++i) {
        float x0 = v[i].x, x1 = v[i].y, x2 = v[i].z, x3 = v[i].w;
        _Float16 h0 = (_Float16)x0, h1 = (_Float16)x1;
        _Float16 h2 = (_Float16)x2, h3 = (_Float16)x3;
        _Float16 l0 = (_Float16)((x0 - (float)h0) * LOSC);
        _Float16 l1 = (_Float16)((x1 - (float)h1) * LOSC);
        _Float16 l2 = (_Float16)((x2 - (float)h2) * LOSC);
        _Float16 l3 = (_Float16)((x3 - (float)h3) * LOSC);
        int w = i >> 1, e = (i & 1) * 4;
        hi[w][e + 0] = h0; hi[w][e + 1] = h1; hi[w][e + 2] = h2; hi[w][e + 3] = h3;
        lo[w][e + 0] = l0; lo[w][e + 1] = l1; lo[w][e + 2] = l2; lo[w][e + 3] = l3;
    }
}

__global__ __launch_bounds__(256)
void argmin_mfma(const float* __restrict__ f, const float* __restrict__ code,
                 const float* __restrict__ cnorm, float4* __restrict__ part) {
    __shared__ _Float16 A1[128 * LSTR];
    __shared__ _Float16 A2[128 * LSTR];
    __shared__ _Float16 B1[128 * LSTR];
    __shared__ _Float16 B2[128 * LSTR];
    __shared__ float4 msm[128][2];

    int t = threadIdx.x;
    int lane = t & 63, wid = t >> 6;
    int wr = wid >> 1, wc = wid & 1;
    int sp = blockIdx.x;
    int rb = blockIdx.y * 128;
    int kb = sp * 1024;

    int srow = t >> 1, sq = (t & 1) * 16;
    const float* gA = f    + (size_t)(rb + srow) * CDIM + sq;
    const float* gB = code + (size_t)(kb + srow) * CDIM + sq;
    int lws = srow * LSTR + sq;

    int rA = (wr * 64 + (lane & 15)) * LSTR + (lane >> 4) * 8;
    int rB = (wc * 64 + (lane & 15)) * LSTR + (lane >> 4) * 8;

    float bv1[4][4], bv2[4][4];
    int   bi1[4][4], bi2[4][4];
#pragma unroll
    for (int m = 0; m < 4; ++m)
#pragma unroll
        for (int i = 0; i < 4; ++i) {
            bv1[m][i] = 3.0e38f; bv2[m][i] = 3.0e38f;
            bi1[m][i] = 0x7fffffff; bi2[m][i] = 0x7fffffff;
        }

    for (int ct = 0; ct < NT8; ++ct) {
        f32x4 acch[4][4], accl[4][4];
#pragma unroll
        for (int m = 0; m < 4; ++m)
#pragma unroll
            for (int n = 0; n < 4; ++n) { acch[m][n] = (f32x4)0.f; accl[m][n] = (f32x4)0.f; }

        for (int cc = 0; cc < 16; ++cc) {
            float4 va[4], vb[4];
            const float* pa = gA + cc * 32;
            const float* pb = gB + (size_t)ct * 128 * CDIM + cc * 32;
#pragma unroll
            for (int i = 0; i < 4; ++i) {
                va[i] = *(const float4*)(pa + i * 4);
                vb[i] = *(const float4*)(pb + i * 4);
            }
            hf8 ha1[2], ha2[2], hb1[2], hb2[2];
            cvt16h(va, ha1, ha2);
            cvt16h(vb, hb1, hb2);

            __syncthreads();
            *(hf8*)&A1[lws] = ha1[0]; *(hf8*)&A1[lws + 8] = ha1[1];
            *(hf8*)&A2[lws] = ha2[0]; *(hf8*)&A2[lws + 8] = ha2[1];
            *(hf8*)&B1[lws] = hb1[0]; *(hf8*)&B1[lws + 8] = hb1[1];
            *(hf8*)&B2[lws] = hb2[0]; *(hf8*)&B2[lws + 8] = hb2[1];
            __syncthreads();

            hf8 b1[4], b2[4];
#pragma unroll
            for (int n = 0; n < 4; ++n) {
                b1[n] = *(hf8*)&B1[rB + n * 16 * LSTR];
                b2[n] = *(hf8*)&B2[rB + n * 16 * LSTR];
            }
#pragma unroll
            for (int m = 0; m < 4; ++m) {
                hf8 am1 = *(hf8*)&A1[rA + m * 16 * LSTR];
                hf8 am2 = *(hf8*)&A2[rA + m * 16 * LSTR];
#pragma unroll
                for (int n = 0; n < 4; ++n) {
                    acch[m][n] = __builtin_amdgcn_mfma_f32_16x16x32_f16(am1, b1[n], acch[m][n], 0, 0, 0);
                    accl[m][n] = __builtin_amdgcn_mfma_f32_16x16x32_f16(am1, b2[n], accl[m][n], 0, 0, 0);
                    accl[m][n] = __builtin_amdgcn_mfma_f32_16x16x32_f16(am2, b1[n], accl[m][n], 0, 0, 0);
                }
            }
        }
#pragma unroll
        for (int m = 0; m < 4; ++m)
#pragma unroll
            for (int i = 0; i < 4; ++i)
#pragma unroll
                for (int n = 0; n < 4; ++n) {
                    int kcode = kb + ct * 128 + wc * 64 + n * 16 + (lane & 15);
                    float dot = acch[m][n][i] + accl[m][n][i] * ILOSC;
                    float d = fmaf(-2.f, dot, cnorm[kcode]);
                    if (d < bv1[m][i]) {
                        bv2[m][i] = bv1[m][i]; bi2[m][i] = bi1[m][i];
                        bv1[m][i] = d;         bi1[m][i] = kcode;
                    } else if (d < bv2[m][i]) {
                        bv2[m][i] = d; bi2[m][i] = kcode;
                    }
                }
    }

    int g = lane >> 4;
#pragma unroll
    for (int m = 0; m < 4; ++m)
#pragma unroll
        for (int i = 0; i < 4; ++i) {
            float v1 = bv1[m][i], v2 = bv2[m][i];
            int   i1 = bi1[m][i], i2 = bi2[m][i];
#pragma unroll
            for (int off = 1; off < 16; off <<= 1) {
                float ov1 = __shfl_xor(v1, off, 64); int oi1 = __shfl_xor(i1, off, 64);
                float ov2 = __shfl_xor(v2, off, 64); int oi2 = __shfl_xor(i2, off, 64);
                if (ov1 < v1 || (ov1 == v1 && oi1 < i1)) {
                    float tv = v1; int ti = i1;
                    v1 = ov1; i1 = oi1; ov1 = tv; oi1 = ti;
                }
                if (ov1 < v2 || (ov1 == v2 && oi1 < i2)) { v2 = ov1; i2 = oi1; }
                if (ov2 < v2 || (ov2 == v2 && oi2 < i2)) { v2 = ov2; i2 = oi2; }
            }
            if ((lane & 15) == 0)
                msm[wr * 64 + m * 16 + g * 4 + i][wc] =
                    make_float4(v1, __int_as_float(i1), v2, __int_as_float(i2));
        }
    __syncthreads();
    if (t < 128) {
        float4 q0 = msm[t][0], q1 = msm[t][1];
        float v1 = q0.x, v2 = q0.z;
        int   i1 = __float_as_int(q0.y), i2 = __float_as_int(q0.w);
        float ov1 = q1.x, ov2 = q1.z;
        int   oi1 = __float_as_int(q1.y), oi2 = __float_as_int(q1.w);
        if (ov1 < v1 || (ov1 == v1 && oi1 < i1)) {
            float tv = v1; int ti = i1;
            v1 = ov1; i1 = oi1; ov1 = tv; oi1 = ti;
        }
        if (ov1 < v2 || (ov1 == v2 && oi1 < i2)) { v2 = ov1; i2 = oi1; }
        if (ov2 < v2 || (ov2 == v2 && oi2 < i2)) { v2 = ov2; i2 = oi2; }
        part[(size_t)sp * NR + rb + t] =
            make_float4(v1, __int_as_float(i1), v2, __int_as_float(i2));
    }
}

// combine nspl partials per row; fp64 re-check when top-2 gap < TAU
__global__ __launch_bounds__(256)
void combine_fix(const float4* __restrict__ part, const float* __restrict__ f,
                 const float* __restrict__ code, int* __restrict__ idx, int nspl) {
    int n = blockIdx.x * 256 + threadIdx.x;
    if (n >= NR) return;
    float bv1 = 3.0e38f, bv2 = 3.0e38f;
    int bi1 = 0x7fffffff, bi2 = 0x7fffffff;
    for (int p = 0; p < nspl; ++p) {
        float4 q = part[(size_t)p * NR + n];
        float ov1 = q.x, ov2 = q.z;
        int oi1 = __float_as_int(q.y), oi2 = __float_as_int(q.w);
        if (ov1 < bv1 || (ov1 == bv1 && oi1 < bi1)) {
            float tv = bv1; int ti = bi1;
            bv1 = ov1; bi1 = oi1; ov1 = tv; oi1 = ti;
        }
        if (ov1 < bv2 || (ov1 == bv2 && oi1 < bi2)) { bv2 = ov1; bi2 = oi1; }
        if (ov2 < bv2 || (ov2 == bv2 && oi2 < bi2)) { bv2 = ov2; bi2 = oi2; }
    }
    bi1 = min(max(bi1, 0), KC - 1);
    bi2 = min(max(bi2, 0), KC - 1);
    if (bv2 - bv1 < TAU) {
        const float* fr = f + (size_t)n * CDIM;
        const float* ca = code + (size_t)bi1 * CDIM;
        const float* cb = code + (size_t)bi2 * CDIM;
        double d1 = 0.0, d2 = 0.0;
        for (int j = 0; j < CDIM; ++j) {
            double fv = fr[j], av = ca[j], bv = cb[j];
            d1 += av * av - 2.0 * fv * av;
            d2 += bv * bv - 2.0 * fv * bv;
        }
        if (d2 < d1 || (d2 == d1 && bi2 < bi1)) bi1 = bi2;
    }
    idx[n] = bi1;
}

// ------------------------------------------------------------ update stage
__global__ __launch_bounds__(256)
void vq_update(float* __restrict__ f, const float* __restrict__ code,
               const int* __restrict__ idx, float* __restrict__ xout,
               const float* __restrict__ x1p, const float* __restrict__ x2p,
               float* __restrict__ reconp, float* __restrict__ lacc) {
    __shared__ float qt[32][33];
    __shared__ float wsum[4];
    int b = blockIdx.z, c0 = blockIdx.y * 32, h0 = blockIdx.x * 32;
    int t = threadIdx.x;
    int tx = t & 31, ty0 = t >> 5;
    float lsum = 0.f;
#pragma unroll
    for (int it = 0; it < 4; ++it) {
        int hwl = ty0 + it * 8;
        int hw = h0 + hwl;
        float qv = 0.f;
        if (hw < HWN) {
            int n = b * HWN + hw;
            size_t fo = (size_t)n * CDIM + c0 + tx;
            float fv = f[fo];
            qv = code[(size_t)idx[n] * CDIM + c0 + tx];
            float rem = fv - qv;
            f[fo] = rem;
            lsum += rem * rem;
        }
        qt[tx][hwl] = qv;
    }
    __syncthreads();
    {
        int hl = t & 31, cl0 = t >> 5;
#pragma unroll
        for (int it = 0; it < 4; ++it) {
            int cl = cl0 + it * 8;
            int hw = h0 + hl;
            if (hw < HWN) {
                size_t off = ((size_t)b * CDIM + c0 + cl) * HWN + hw;
                float qv = qt[cl][hl];
                xout[off] = qv;
                if (reconp) reconp[off] = qv + x1p[off] + x2p[off];
            }
        }
    }
#pragma unroll
    for (int off = 32; off; off >>= 1) lsum += __shfl_down(lsum, off);
    int lane = t & 63, w = t >> 6;
    if (lane == 0) wsum[w] = lsum;
    __syncthreads();
    if (t == 0) atomicAdd(lacc, wsum[0] + wsum[1] + wsum[2] + wsum[3]);
}

__global__ void finalize_losses(const float* __restrict__ lacc, float* __restrict__ out) {
    int t = threadIdx.x;
    if (t < 3) out[t] = 2.0f * lacc[t] / (float)ETOT;
}

// ------------------------------------------------------------------- launch

extern "C" void kernel_launch(void* const* d_in, const int* in_sizes, int n_in,
                              void* d_out, int out_size, void* d_ws, size_t ws_size,
                              hipStream_t stream) {
    (void)in_sizes; (void)n_in; (void)out_size;
    const float* head = (const float*)d_in[0];
    const float* cbs[3] = {(const float*)d_in[1], (const float*)d_in[2], (const float*)d_in[3]};
    float* out = (float*)d_out;
    char* ws = (char*)d_ws;

    // fast-path ws layout
    size_t o_f = 0;
    size_t o_fs   = o_f   + ETOT * 4;                 // 25,690,112
    size_t o_cs   = o_fs  + (size_t)NR * 1024 * 2;    // 51,380,224
    size_t o_part = o_cs  + (size_t)KC * 1024 * 2;    // 55,574,528
    size_t o_idx  = o_part + (size_t)NSTRIP * NR * 16;
    size_t o_cn   = o_idx + (size_t)NR * 4;
    size_t o_la   = o_cn  + (size_t)KC * 4;
    size_t fast_need = o_la + 64;                     // ~58.85 MB

    if (ws_size >= fast_need) {
        float*     f     = (float*)(ws + o_f);
        _Float16*  fs    = (_Float16*)(ws + o_fs);
        _Float16*  cspl  = (_Float16*)(ws + o_cs);
        float4*    part  = (float4*)(ws + o_part);
        int*       idx   = (int*)(ws + o_idx);
        float*     cnorm = (float*)(ws + o_cn);
        float*     lacc  = (float*)(ws + o_la);

        zero_acc<<<1, 64, 0, stream>>>(lacc);
        transpose_head<<<dim3(25, 16, 16), 256, 0, stream>>>(head, f);
        for (int s = 0; s < 3; ++s) {
            code_norms1<<<dim3(KC), 64, 0, stream>>>(cbs[s], cnorm);
            split_rows<<<dim3(KC * 64 / 256), 256, 0, stream>>>(cbs[s], cspl, KC);
            split_rows<<<dim3(NR * 64 / 256), 256, 0, stream>>>(f, fs, NR);
            argmin_fast<<<dim3(NSTRIP, 98), 256, 0, stream>>>(fs, cspl, cnorm, part);
            combine_fix<<<dim3((NR + 255) / 256), 256, 0, stream>>>(part, f, cbs[s], idx, NSTRIP);
            float* xout   = out + (size_t)s * ETOT;
            float* reconp = (s == 2) ? out + 3 * ETOT + 3 : nullptr;
            vq_update<<<dim3(25, 16, 16), 256, 0, stream>>>(f, cbs[s], idx, xout,
                                                            out, out + ETOT, reconp, lacc + s);
        }
        finalize_losses<<<1, 64, 0, stream>>>(lacc, out + 3 * ETOT);
        return;
    }

    // fallback: round-5 proven layout (<= 26.15 MB)
    float*  f     = (float*)ws;              size_t off = ETOT * 4;
    float4* part  = (float4*)(ws + off);     off += (size_t)NSPL * NR * 16;
    int*    idx   = (int*)(ws + off);        off += (size_t)NR * 4;
    float*  cnorm = (float*)(ws + off);      off += (size_t)KC * 4;
    float*  lacc  = (float*)(ws + off);      off += 16;

    zero_acc<<<1, 64, 0, stream>>>(lacc);
    transpose_head<<<dim3(25, 16, 16), 256, 0, stream>>>(head, f);
    for (int s = 0; s < 3; ++s) {
        code_norms1<<<dim3(KC), 64, 0, stream>>>(cbs[s], cnorm);
        argmin_mfma<<<dim3(NSPL, 98), 256, 0, stream>>>(f, cbs[s], cnorm, part);
        combine_fix<<<dim3((NR + 255) / 256), 256, 0, stream>>>(part, f, cbs[s], idx, NSPL);
        float* xout   = out + (size_t)s * ETOT;
        float* reconp = (s == 2) ? out + 3 * ETOT + 3 : nullptr;
        vq_update<<<dim3(25, 16, 16), 256, 0, stream>>>(f, cbs[s], idx, xout,
                                                        out, out + ETOT, reconp, lacc + s);
    }
    finalize_losses<<<1, 64, 0, stream>>>(lacc, out + 3 * ETOT);
}

// Round 9
// 869.814 us; speedup vs baseline: 2.5888x; 1.0099x over previous
//
#include <hip/hip_runtime.h>
#include <cstddef>

#define BB    16
#define CDIM  512
#define HWN   784
#define KC    2048
#define NR    (BB*HWN)                  // 12544 rows (= 98*128)
#define ETOT  ((size_t)BB*CDIM*HWN)     // 6422528 elements per tensor
#define NSTRIP 16                       // code strips of 128
#define TAU   0.02f
#define TSZ   (128*32)                  // one K-chunk plane tile in halves

typedef _Float16 hf8 __attribute__((ext_vector_type(8)));
typedef float f32x4 __attribute__((ext_vector_type(4)));

__device__ __forceinline__ void gload_lds16(const void* g, void* l) {
    __builtin_amdgcn_global_load_lds((const __attribute__((address_space(1))) void*)g,
                                     (__attribute__((address_space(3))) void*)l, 16, 0, 0);
}

// ---------------------------------------------------------------- utilities

__global__ void zero_acc(float* lacc) {
    if (threadIdx.x < 3) lacc[threadIdx.x] = 0.f;
}

// head (B,C,HW) -> f rows (fp32) AND fs split rows (f16 [hi(512)|lo(512)])
__global__ __launch_bounds__(256)
void transpose_head_split(const float* __restrict__ head, float* __restrict__ f,
                          _Float16* __restrict__ fs) {
    __shared__ float tile[32][33];
    int b = blockIdx.z, c0 = blockIdx.y * 32, h0 = blockIdx.x * 32;
    int t = threadIdx.x;
    const float* src = head + (size_t)b * CDIM * HWN;
    {
        int hl = t & 31, cl0 = t >> 5;
#pragma unroll
        for (int it = 0; it < 4; ++it) {
            int cl = cl0 + it * 8;
            int hw = h0 + hl;
            if (hw < HWN) tile[cl][hl] = src[(size_t)(c0 + cl) * HWN + hw];
        }
    }
    __syncthreads();
    float* dst = f + (size_t)b * HWN * CDIM;
    _Float16* dsts = fs + (size_t)b * HWN * 1024;
    {
        int cl = t & 31, hl0 = t >> 5;
#pragma unroll
        for (int it = 0; it < 4; ++it) {
            int hl = hl0 + it * 8;
            int hw = h0 + hl;
            if (hw < HWN) {
                float v = tile[cl][hl];
                dst[(size_t)hw * CDIM + c0 + cl] = v;
                _Float16 h = (_Float16)v;
                dsts[(size_t)hw * 1024 + c0 + cl] = h;
                dsts[(size_t)hw * 1024 + 512 + c0 + cl] = (_Float16)(v - (float)h);
            }
        }
    }
}

// codebook fp32 [K][512] -> f16 split [K][1024] + ||row||^2 (one wave per row)
__global__ __launch_bounds__(256)
void split_code_norm(const float* __restrict__ src, _Float16* __restrict__ dst,
                     float* __restrict__ cnorm) {
    int tid = blockIdx.x * 256 + threadIdx.x;        // 8 elems per thread
    int row = tid >> 6, c8 = (tid & 63) * 8;
    const float* p = src + (size_t)row * CDIM + c8;
    float4 v0 = *(const float4*)p, v1 = *(const float4*)(p + 4);
    hf8 hi, lo;
    float x[8] = {v0.x, v0.y, v0.z, v0.w, v1.x, v1.y, v1.z, v1.w};
    float s = 0.f;
#pragma unroll
    for (int j = 0; j < 8; ++j) {
        _Float16 h = (_Float16)x[j];
        hi[j] = h;
        lo[j] = (_Float16)(x[j] - (float)h);
        s += x[j] * x[j];
    }
    *(hf8*)&dst[(size_t)row * 1024 + c8] = hi;
    *(hf8*)&dst[(size_t)row * 1024 + 512 + c8] = lo;
#pragma unroll
    for (int off = 32; off; off >>= 1) s += __shfl_down(s, off);
    if ((threadIdx.x & 63) == 0) cnorm[row] = s;
}

// --------------------------------------------------- MFMA argmin (3-plane)
// grid (16 strips, 98 row tiles), block 256 (4 waves, 2x2 of 64x64).
// Per K-chunk (32 halves) stage Ah,Al,Bh,Bl tiles via global_load_lds
// (double-buffered, plain __syncthreads ordering — R8-proven). Per (m,n):
// acc += ah*bh + ah*bl + al*bh  (error = lo*clo ~ 3e-6, R6-proven).
__global__ __launch_bounds__(256)
void argmin_fast(const _Float16* __restrict__ fs, const _Float16* __restrict__ cs,
                 const float* __restrict__ cnorm, float4* __restrict__ part) {
    __shared__ _Float16 Ah[2 * TSZ];
    __shared__ _Float16 Al[2 * TSZ];
    __shared__ _Float16 Bh[2 * TSZ];
    __shared__ _Float16 Bl[2 * TSZ];
    __shared__ float4 msm[128][2];

    int t = threadIdx.x;
    int lane = t & 63, w = t >> 6;
    int wr = w >> 1, wc = w & 1;
    int rb = blockIdx.y * 128, cb = blockIdx.x * 128;

    // staging: thread t owns LDS granules t and 256+t (16B, linear dest) in
    // each plane tile; source granule XOR-swizzled (R6/R8-proven pattern).
    int r1 = t >> 2, s1 = t & 3;
    int sg = s1 ^ ((r1 >> 1) & 3);           // same for row r1+64
    const _Float16* gA1 = fs + (size_t)(rb + r1) * 1024 + sg * 8;
    const _Float16* gA2 = fs + (size_t)(rb + 64 + r1) * 1024 + sg * 8;
    const _Float16* gB1 = cs + (size_t)(cb + r1) * 1024 + sg * 8;
    const _Float16* gB2 = cs + (size_t)(cb + 64 + r1) * 1024 + sg * 8;
    int d1 = t * 8, d2 = (256 + t) * 8;

    // fragment read addressing (swizzle term constant across m/n)
    int frA = wr * 64 + (lane & 15);
    int frB = wc * 64 + (lane & 15);
    int fslot = lane >> 4;
    int oA = frA * 32 + (fslot ^ ((frA >> 1) & 3)) * 8;
    int oB = frB * 32 + (fslot ^ ((frB >> 1) & 3)) * 8;

    f32x4 acc[4][4];
#pragma unroll
    for (int m = 0; m < 4; ++m)
#pragma unroll
        for (int n = 0; n < 4; ++n) acc[m][n] = (f32x4)0.f;

#define STAGE(P, KK) do {                                                   \
        int _bo = (P) * TSZ, _ko = (KK) * 32;                               \
        gload_lds16(gA1 + _ko,       &Ah[_bo + d1]);                        \
        gload_lds16(gA2 + _ko,       &Ah[_bo + d2]);                        \
        gload_lds16(gA1 + _ko + 512, &Al[_bo + d1]);                        \
        gload_lds16(gA2 + _ko + 512, &Al[_bo + d2]);                        \
        gload_lds16(gB1 + _ko,       &Bh[_bo + d1]);                        \
        gload_lds16(gB2 + _ko,       &Bh[_bo + d2]);                        \
        gload_lds16(gB1 + _ko + 512, &Bl[_bo + d1]);                        \
        gload_lds16(gB2 + _ko + 512, &Bl[_bo + d2]);                        \
    } while (0)

    STAGE(0, 0);
    __syncthreads();                         // chunk 0 resident
    for (int kk = 0; kk < 16; ++kk) {
        if (kk < 15) STAGE((kk + 1) & 1, kk + 1);   // DMA overlaps compute
        int bo = (kk & 1) * TSZ;
        hf8 ah[4], al[4], bh[4], bl[4];
#pragma unroll
        for (int n = 0; n < 4; ++n) {
            bh[n] = *(hf8*)&Bh[bo + oB + n * 512];
            bl[n] = *(hf8*)&Bl[bo + oB + n * 512];
        }
#pragma unroll
        for (int m = 0; m < 4; ++m) {
            ah[m] = *(hf8*)&Ah[bo + oA + m * 512];
            al[m] = *(hf8*)&Al[bo + oA + m * 512];
        }
#pragma unroll
        for (int m = 0; m < 4; ++m)
#pragma unroll
            for (int n = 0; n < 4; ++n) {
                acc[m][n] = __builtin_amdgcn_mfma_f32_16x16x32_f16(ah[m], bh[n], acc[m][n], 0, 0, 0);
                acc[m][n] = __builtin_amdgcn_mfma_f32_16x16x32_f16(ah[m], bl[n], acc[m][n], 0, 0, 0);
                acc[m][n] = __builtin_amdgcn_mfma_f32_16x16x32_f16(al[m], bh[n], acc[m][n], 0, 0, 0);
            }
        __syncthreads();                     // drains DMA + LDS reads done
    }
#undef STAGE

    // per-lane top-2 over n, butterfly over 16 cols, deposit per (row, wc).
    // D layout: col = lane&15, row = (lane>>4)*4 + i.
    int g = lane >> 4;
#pragma unroll
    for (int m = 0; m < 4; ++m)
#pragma unroll
        for (int i = 0; i < 4; ++i) {
            float v1 = 3.0e38f, v2 = 3.0e38f;
            int i1 = 0x7fffffff, i2 = 0x7fffffff;
#pragma unroll
            for (int n = 0; n < 4; ++n) {
                int kcode = cb + wc * 64 + n * 16 + (lane & 15);
                float d = fmaf(-2.f, acc[m][n][i], cnorm[kcode]);
                if (d < v1) { v2 = v1; i2 = i1; v1 = d; i1 = kcode; }
                else if (d < v2) { v2 = d; i2 = kcode; }
            }
#pragma unroll
            for (int off = 1; off < 16; off <<= 1) {
                float ov1 = __shfl_xor(v1, off, 64); int oi1 = __shfl_xor(i1, off, 64);
                float ov2 = __shfl_xor(v2, off, 64); int oi2 = __shfl_xor(i2, off, 64);
                if (ov1 < v1 || (ov1 == v1 && oi1 < i1)) {
                    float tv = v1; int ti = i1;
                    v1 = ov1; i1 = oi1; ov1 = tv; oi1 = ti;
                }
                if (ov1 < v2 || (ov1 == v2 && oi1 < i2)) { v2 = ov1; i2 = oi1; }
                if (ov2 < v2 || (ov2 == v2 && oi2 < i2)) { v2 = ov2; i2 = oi2; }
            }
            if ((lane & 15) == 0)
                msm[wr * 64 + m * 16 + g * 4 + i][wc] =
                    make_float4(v1, __int_as_float(i1), v2, __int_as_float(i2));
        }
    __syncthreads();
    if (t < 128) {
        float4 q0 = msm[t][0], q1 = msm[t][1];
        float v1 = q0.x, v2 = q0.z;
        int   i1 = __float_as_int(q0.y), i2 = __float_as_int(q0.w);
        float ov1 = q1.x, ov2 = q1.z;
        int   oi1 = __float_as_int(q1.y), oi2 = __float_as_int(q1.w);
        if (ov1 < v1 || (ov1 == v1 && oi1 < i1)) {
            float tv = v1; int ti = i1;
            v1 = ov1; i1 = oi1; ov1 = tv; oi1 = ti;
        }
        if (ov1 < v2 || (ov1 == v2 && oi1 < i2)) { v2 = ov1; i2 = oi1; }
        if (ov2 < v2 || (ov2 == v2 && oi2 < i2)) { v2 = ov2; i2 = oi2; }
        part[(size_t)blockIdx.x * NR + rb + t] =
            make_float4(v1, __int_as_float(i1), v2, __int_as_float(i2));
    }
}

// combine NSTRIP partials per row; fp64 re-check when top-2 gap < TAU
__global__ __launch_bounds__(256)
void combine_fix(const float4* __restrict__ part, const float* __restrict__ f,
                 const float* __restrict__ code, int* __restrict__ idx) {
    int n = blockIdx.x * 256 + threadIdx.x;
    if (n >= NR) return;
    float bv1 = 3.0e38f, bv2 = 3.0e38f;
    int bi1 = 0x7fffffff, bi2 = 0x7fffffff;
    for (int p = 0; p < NSTRIP; ++p) {
        float4 q = part[(size_t)p * NR + n];
        float ov1 = q.x, ov2 = q.z;
        int oi1 = __float_as_int(q.y), oi2 = __float_as_int(q.w);
        if (ov1 < bv1 || (ov1 == bv1 && oi1 < bi1)) {
            float tv = bv1; int ti = bi1;
            bv1 = ov1; bi1 = oi1; ov1 = tv; oi1 = ti;
        }
        if (ov1 < bv2 || (ov1 == bv2 && oi1 < bi2)) { bv2 = ov1; bi2 = oi1; }
        if (ov2 < bv2 || (ov2 == bv2 && oi2 < bi2)) { bv2 = ov2; bi2 = oi2; }
    }
    bi1 = min(max(bi1, 0), KC - 1);
    bi2 = min(max(bi2, 0), KC - 1);
    if (bv2 - bv1 < TAU) {
        const float* fr = f + (size_t)n * CDIM;
        const float* ca = code + (size_t)bi1 * CDIM;
        const float* cb = code + (size_t)bi2 * CDIM;
        double d1 = 0.0, d2 = 0.0;
        for (int j = 0; j < CDIM; ++j) {
            double fv = fr[j], av = ca[j], bv = cb[j];
            d1 += av * av - 2.0 * fv * av;
            d2 += bv * bv - 2.0 * fv * bv;
        }
        if (d2 < d1 || (d2 == d1 && bi2 < bi1)) bi1 = bi2;
    }
    idx[n] = bi1;
}

// ------------------------------------------------------------ update stage
// Also emits f16 split of the new residual (for the NEXT stage's argmin)
// when fsout != nullptr.
__global__ __launch_bounds__(256)
void vq_update(float* __restrict__ f, const float* __restrict__ code,
               const int* __restrict__ idx, float* __restrict__ xout,
               const float* __restrict__ x1p, const float* __restrict__ x2p,
               float* __restrict__ reconp, _Float16* __restrict__ fsout,
               float* __restrict__ lacc) {
    __shared__ float qt[32][33];
    __shared__ float wsum[4];
    int b = blockIdx.z, c0 = blockIdx.y * 32, h0 = blockIdx.x * 32;
    int t = threadIdx.x;
    int tx = t & 31, ty0 = t >> 5;
    float lsum = 0.f;
#pragma unroll
    for (int it = 0; it < 4; ++it) {
        int hwl = ty0 + it * 8;
        int hw = h0 + hwl;
        float qv = 0.f;
        if (hw < HWN) {
            int n = b * HWN + hw;
            size_t fo = (size_t)n * CDIM + c0 + tx;
            float fv = f[fo];
            qv = code[(size_t)idx[n] * CDIM + c0 + tx];
            float rem = fv - qv;
            f[fo] = rem;
            lsum += rem * rem;
            if (fsout) {
                _Float16 h = (_Float16)rem;
                fsout[(size_t)n * 1024 + c0 + tx] = h;
                fsout[(size_t)n * 1024 + 512 + c0 + tx] = (_Float16)(rem - (float)h);
            }
        }
        qt[tx][hwl] = qv;
    }
    __syncthreads();
    {
        int hl = t & 31, cl0 = t >> 5;
#pragma unroll
        for (int it = 0; it < 4; ++it) {
            int cl = cl0 + it * 8;
            int hw = h0 + hl;
            if (hw < HWN) {
                size_t off = ((size_t)b * CDIM + c0 + cl) * HWN + hw;
                float qv = qt[cl][hl];
                xout[off] = qv;
                if (reconp) reconp[off] = qv + x1p[off] + x2p[off];
            }
        }
    }
#pragma unroll
    for (int off = 32; off; off >>= 1) lsum += __shfl_down(lsum, off);
    int lane = t & 63, w = t >> 6;
    if (lane == 0) wsum[w] = lsum;
    __syncthreads();
    if (t == 0) atomicAdd(lacc, wsum[0] + wsum[1] + wsum[2] + wsum[3]);
}

__global__ void finalize_losses(const float* __restrict__ lacc, float* __restrict__ out) {
    int t = threadIdx.x;
    if (t < 3) out[t] = 2.0f * lacc[t] / (float)ETOT;
}

// ------------------------------------------------------------------- launch

extern "C" void kernel_launch(void* const* d_in, const int* in_sizes, int n_in,
                              void* d_out, int out_size, void* d_ws, size_t ws_size,
                              hipStream_t stream) {
    (void)in_sizes; (void)n_in; (void)out_size; (void)ws_size;
    const float* head = (const float*)d_in[0];
    const float* cbs[3] = {(const float*)d_in[1], (const float*)d_in[2], (const float*)d_in[3]};
    float* out = (float*)d_out;
    char* ws = (char*)d_ws;

    size_t o_f = 0;
    size_t o_fs   = o_f   + ETOT * 4;
    size_t o_cs   = o_fs  + (size_t)NR * 1024 * 2;
    size_t o_part = o_cs  + (size_t)KC * 1024 * 2;
    size_t o_idx  = o_part + (size_t)NSTRIP * NR * 16;
    size_t o_cn   = o_idx + (size_t)NR * 4;
    size_t o_la   = o_cn  + (size_t)KC * 4;      // total ~58.85 MB (proven fits, R6)

    float*     f     = (float*)(ws + o_f);
    _Float16*  fs    = (_Float16*)(ws + o_fs);
    _Float16*  cspl  = (_Float16*)(ws + o_cs);
    float4*    part  = (float4*)(ws + o_part);
    int*       idx   = (int*)(ws + o_idx);
    float*     cnorm = (float*)(ws + o_cn);
    float*     lacc  = (float*)(ws + o_la);

    zero_acc<<<1, 64, 0, stream>>>(lacc);
    transpose_head_split<<<dim3(25, 16, 16), 256, 0, stream>>>(head, f, fs);
    for (int s = 0; s < 3; ++s) {
        split_code_norm<<<dim3(KC * 64 / 256), 256, 0, stream>>>(cbs[s], cspl, cnorm);
        argmin_fast<<<dim3(NSTRIP, 98), 256, 0, stream>>>(fs, cspl, cnorm, part);
        combine_fix<<<dim3((NR + 255) / 256), 256, 0, stream>>>(part, f, cbs[s], idx);
        float* xout   = out + (size_t)s * ETOT;
        float* reconp = (s == 2) ? out + 3 * ETOT + 3 : nullptr;
        _Float16* fsout = (s < 2) ? fs : nullptr;
        vq_update<<<dim3(25, 16, 16), 256, 0, stream>>>(f, cbs[s], idx, xout,
                                                        out, out + ETOT, reconp,
                                                        fsout, lacc + s);
    }
    finalize_losses<<<1, 64, 0, stream>>>(lacc, out + 3 * ETOT);
}

// Round 10
// 766.152 us; speedup vs baseline: 2.9391x; 1.1353x over previous
//
#include <hip/hip_runtime.h>
#include <cstddef>

#define BB    16
#define CDIM  512
#define HWN   784
#define KC    2048
#define NR    (BB*HWN)                  // 12544 rows (= 49*256)
#define ETOT  ((size_t)BB*CDIM*HWN)     // 6422528 elements per tensor
#define NSTRIP 16                       // code strips of 128
#define TAU   0.02f
#define ATSZ  (256*32)                  // A plane tile (halves)
#define BTSZ  (128*32)                  // B plane tile (halves)

typedef _Float16 hf8 __attribute__((ext_vector_type(8)));
typedef float f32x4 __attribute__((ext_vector_type(4)));

__device__ __forceinline__ void gload_lds16(const void* g, void* l) {
    __builtin_amdgcn_global_load_lds((const __attribute__((address_space(1))) void*)g,
                                     (__attribute__((address_space(3))) void*)l, 16, 0, 0);
}

// ---------------------------------------------------------------- utilities

__global__ void zero_acc(float* lacc) {
    if (threadIdx.x < 3) lacc[threadIdx.x] = 0.f;
}

// head (B,C,HW) -> f rows (fp32) AND fs split rows (f16 [hi(512)|lo(512)])
__global__ __launch_bounds__(256)
void transpose_head_split(const float* __restrict__ head, float* __restrict__ f,
                          _Float16* __restrict__ fs) {
    __shared__ float tile[32][33];
    int b = blockIdx.z, c0 = blockIdx.y * 32, h0 = blockIdx.x * 32;
    int t = threadIdx.x;
    const float* src = head + (size_t)b * CDIM * HWN;
    {
        int hl = t & 31, cl0 = t >> 5;
#pragma unroll
        for (int it = 0; it < 4; ++it) {
            int cl = cl0 + it * 8;
            int hw = h0 + hl;
            if (hw < HWN) tile[cl][hl] = src[(size_t)(c0 + cl) * HWN + hw];
        }
    }
    __syncthreads();
    float* dst = f + (size_t)b * HWN * CDIM;
    _Float16* dsts = fs + (size_t)b * HWN * 1024;
    {
        int cl = t & 31, hl0 = t >> 5;
#pragma unroll
        for (int it = 0; it < 4; ++it) {
            int hl = hl0 + it * 8;
            int hw = h0 + hl;
            if (hw < HWN) {
                float v = tile[cl][hl];
                dst[(size_t)hw * CDIM + c0 + cl] = v;
                _Float16 h = (_Float16)v;
                dsts[(size_t)hw * 1024 + c0 + cl] = h;
                dsts[(size_t)hw * 1024 + 512 + c0 + cl] = (_Float16)(v - (float)h);
            }
        }
    }
}

// codebook fp32 [K][512] -> f16 split [K][1024] + ||row||^2 (one wave per row)
__global__ __launch_bounds__(256)
void split_code_norm(const float* __restrict__ src, _Float16* __restrict__ dst,
                     float* __restrict__ cnorm) {
    int tid = blockIdx.x * 256 + threadIdx.x;        // 8 elems per thread
    int row = tid >> 6, c8 = (tid & 63) * 8;
    const float* p = src + (size_t)row * CDIM + c8;
    float4 v0 = *(const float4*)p, v1 = *(const float4*)(p + 4);
    hf8 hi, lo;
    float x[8] = {v0.x, v0.y, v0.z, v0.w, v1.x, v1.y, v1.z, v1.w};
    float s = 0.f;
#pragma unroll
    for (int j = 0; j < 8; ++j) {
        _Float16 h = (_Float16)x[j];
        hi[j] = h;
        lo[j] = (_Float16)(x[j] - (float)h);
        s += x[j] * x[j];
    }
    *(hf8*)&dst[(size_t)row * 1024 + c8] = hi;
    *(hf8*)&dst[(size_t)row * 1024 + 512 + c8] = lo;
#pragma unroll
    for (int off = 32; off; off >>= 1) s += __shfl_down(s, off);
    if ((threadIdx.x & 63) == 0) cnorm[row] = s;
}

// --------------------------------------------------- MFMA argmin (3-plane)
// 256 rows x 128 codes per block, 512 threads = 8 waves (4 row-groups x 2
// col-groups; each wave owns 64x64). Single-buffered 4-tile LDS (48KB+8KB),
// serial 2-barrier schedule (R6/R9-proven semantics). grid (16, 49).
__global__ __launch_bounds__(512, 4)
void argmin_fast(const _Float16* __restrict__ fs, const _Float16* __restrict__ cs,
                 const float* __restrict__ cnorm, float4* __restrict__ part) {
    __shared__ _Float16 Ah[ATSZ];
    __shared__ _Float16 Al[ATSZ];
    __shared__ _Float16 Bh[BTSZ];
    __shared__ _Float16 Bl[BTSZ];
    __shared__ float4 msm[256][2];

    int t = threadIdx.x;
    int lane = t & 63, w = t >> 6;
    int wr = w >> 1, wc = w & 1;
    int rb = blockIdx.y * 256, cb = blockIdx.x * 128;

    // staging: A planes rows r=t>>2 and 128+(t>>2) (2 granules each),
    // B planes row t>>2 (1 granule each). LDS dest linear (granule idx = t).
    int r1 = t >> 2, s1 = t & 3;
    int sg = s1 ^ ((r1 >> 1) & 3);           // (r+128)>>1 & 3 identical
    const _Float16* gA1 = fs + (size_t)(rb + r1) * 1024 + sg * 8;
    const _Float16* gA2 = fs + (size_t)(rb + 128 + r1) * 1024 + sg * 8;
    const _Float16* gB1 = cs + (size_t)(cb + r1) * 1024 + sg * 8;
    int d1 = t * 8, d2 = (512 + t) * 8;

    // fragment read addressing: off = row*32 + (fslot ^ ((row>>1)&3))*8;
    // row steps of 16 leave (row>>1)&3 unchanged.
    int frA = wr * 64 + (lane & 15);
    int frB = wc * 64 + (lane & 15);
    int fslot = lane >> 4;
    int oA = frA * 32 + (fslot ^ ((frA >> 1) & 3)) * 8;
    int oB = frB * 32 + (fslot ^ ((frB >> 1) & 3)) * 8;

    f32x4 acc[4][4];
#pragma unroll
    for (int m = 0; m < 4; ++m)
#pragma unroll
        for (int n = 0; n < 4; ++n) acc[m][n] = (f32x4)0.f;

    for (int kk = 0; kk < 16; ++kk) {
        int ko = kk * 32;
        gload_lds16(gA1 + ko,       &Ah[d1]);
        gload_lds16(gA2 + ko,       &Ah[d2]);
        gload_lds16(gA1 + ko + 512, &Al[d1]);
        gload_lds16(gA2 + ko + 512, &Al[d2]);
        gload_lds16(gB1 + ko,       &Bh[d1]);
        gload_lds16(gB1 + ko + 512, &Bl[d1]);
        __syncthreads();                     // drains DMA: tiles resident
        hf8 bh[4], bl[4];
#pragma unroll
        for (int n = 0; n < 4; ++n) {
            bh[n] = *(hf8*)&Bh[oB + n * 512];
            bl[n] = *(hf8*)&Bl[oB + n * 512];
        }
#pragma unroll
        for (int m = 0; m < 4; ++m) {
            hf8 ah = *(hf8*)&Ah[oA + m * 512];
            hf8 al = *(hf8*)&Al[oA + m * 512];
#pragma unroll
            for (int n = 0; n < 4; ++n) {
                acc[m][n] = __builtin_amdgcn_mfma_f32_16x16x32_f16(ah, bh[n], acc[m][n], 0, 0, 0);
                acc[m][n] = __builtin_amdgcn_mfma_f32_16x16x32_f16(ah, bl[n], acc[m][n], 0, 0, 0);
                acc[m][n] = __builtin_amdgcn_mfma_f32_16x16x32_f16(al, bh[n], acc[m][n], 0, 0, 0);
            }
        }
        __syncthreads();                     // reads done: buffer reusable
    }

    // per-lane top-2 over n, butterfly over 16 cols, deposit per (row, wc).
    // D layout: col = lane&15, row = (lane>>4)*4 + i.
    int g = lane >> 4;
#pragma unroll
    for (int m = 0; m < 4; ++m)
#pragma unroll
        for (int i = 0; i < 4; ++i) {
            float v1 = 3.0e38f, v2 = 3.0e38f;
            int i1 = 0x7fffffff, i2 = 0x7fffffff;
#pragma unroll
            for (int n = 0; n < 4; ++n) {
                int kcode = cb + wc * 64 + n * 16 + (lane & 15);
                float d = fmaf(-2.f, acc[m][n][i], cnorm[kcode]);
                if (d < v1) { v2 = v1; i2 = i1; v1 = d; i1 = kcode; }
                else if (d < v2) { v2 = d; i2 = kcode; }
            }
#pragma unroll
            for (int off = 1; off < 16; off <<= 1) {
                float ov1 = __shfl_xor(v1, off, 64); int oi1 = __shfl_xor(i1, off, 64);
                float ov2 = __shfl_xor(v2, off, 64); int oi2 = __shfl_xor(i2, off, 64);
                if (ov1 < v1 || (ov1 == v1 && oi1 < i1)) {
                    float tv = v1; int ti = i1;
                    v1 = ov1; i1 = oi1; ov1 = tv; oi1 = ti;
                }
                if (ov1 < v2 || (ov1 == v2 && oi1 < i2)) { v2 = ov1; i2 = oi1; }
                if (ov2 < v2 || (ov2 == v2 && oi2 < i2)) { v2 = ov2; i2 = oi2; }
            }
            if ((lane & 15) == 0)
                msm[wr * 64 + m * 16 + g * 4 + i][wc] =
                    make_float4(v1, __int_as_float(i1), v2, __int_as_float(i2));
        }
    __syncthreads();
    if (t < 256) {
        float4 q0 = msm[t][0], q1 = msm[t][1];
        float v1 = q0.x, v2 = q0.z;
        int   i1 = __float_as_int(q0.y), i2 = __float_as_int(q0.w);
        float ov1 = q1.x, ov2 = q1.z;
        int   oi1 = __float_as_int(q1.y), oi2 = __float_as_int(q1.w);
        if (ov1 < v1 || (ov1 == v1 && oi1 < i1)) {
            float tv = v1; int ti = i1;
            v1 = ov1; i1 = oi1; ov1 = tv; oi1 = ti;
        }
        if (ov1 < v2 || (ov1 == v2 && oi1 < i2)) { v2 = ov1; i2 = oi1; }
        if (ov2 < v2 || (ov2 == v2 && oi2 < i2)) { v2 = ov2; i2 = oi2; }
        part[(size_t)blockIdx.x * NR + rb + t] =
            make_float4(v1, __int_as_float(i1), v2, __int_as_float(i2));
    }
}

// combine NSTRIP partials per row; fp64 re-check when top-2 gap < TAU
__global__ __launch_bounds__(256)
void combine_fix(const float4* __restrict__ part, const float* __restrict__ f,
                 const float* __restrict__ code, int* __restrict__ idx) {
    int n = blockIdx.x * 256 + threadIdx.x;
    if (n >= NR) return;
    float bv1 = 3.0e38f, bv2 = 3.0e38f;
    int bi1 = 0x7fffffff, bi2 = 0x7fffffff;
    for (int p = 0; p < NSTRIP; ++p) {
        float4 q = part[(size_t)p * NR + n];
        float ov1 = q.x, ov2 = q.z;
        int oi1 = __float_as_int(q.y), oi2 = __float_as_int(q.w);
        if (ov1 < bv1 || (ov1 == bv1 && oi1 < bi1)) {
            float tv = bv1; int ti = bi1;
            bv1 = ov1; bi1 = oi1; ov1 = tv; oi1 = ti;
        }
        if (ov1 < bv2 || (ov1 == bv2 && oi1 < bi2)) { bv2 = ov1; bi2 = oi1; }
        if (ov2 < bv2 || (ov2 == bv2 && oi2 < bi2)) { bv2 = ov2; bi2 = oi2; }
    }
    bi1 = min(max(bi1, 0), KC - 1);
    bi2 = min(max(bi2, 0), KC - 1);
    if (bv2 - bv1 < TAU) {
        const float* fr = f + (size_t)n * CDIM;
        const float* ca = code + (size_t)bi1 * CDIM;
        const float* cb = code + (size_t)bi2 * CDIM;
        double d1 = 0.0, d2 = 0.0;
        for (int j = 0; j < CDIM; ++j) {
            double fv = fr[j], av = ca[j], bv = cb[j];
            d1 += av * av - 2.0 * fv * av;
            d2 += bv * bv - 2.0 * fv * bv;
        }
        if (d2 < d1 || (d2 == d1 && bi2 < bi1)) bi1 = bi2;
    }
    idx[n] = bi1;
}

// ------------------------------------------------------------ update stage
// Also emits f16 split of the new residual (next stage's argmin input).
__global__ __launch_bounds__(256)
void vq_update(float* __restrict__ f, const float* __restrict__ code,
               const int* __restrict__ idx, float* __restrict__ xout,
               const float* __restrict__ x1p, const float* __restrict__ x2p,
               float* __restrict__ reconp, _Float16* __restrict__ fsout,
               float* __restrict__ lacc) {
    __shared__ float qt[32][33];
    __shared__ float wsum[4];
    int b = blockIdx.z, c0 = blockIdx.y * 32, h0 = blockIdx.x * 32;
    int t = threadIdx.x;
    int tx = t & 31, ty0 = t >> 5;
    float lsum = 0.f;
#pragma unroll
    for (int it = 0; it < 4; ++it) {
        int hwl = ty0 + it * 8;
        int hw = h0 + hwl;
        float qv = 0.f;
        if (hw < HWN) {
            int n = b * HWN + hw;
            size_t fo = (size_t)n * CDIM + c0 + tx;
            float fv = f[fo];
            qv = code[(size_t)idx[n] * CDIM + c0 + tx];
            float rem = fv - qv;
            f[fo] = rem;
            lsum += rem * rem;
            if (fsout) {
                _Float16 h = (_Float16)rem;
                fsout[(size_t)n * 1024 + c0 + tx] = h;
                fsout[(size_t)n * 1024 + 512 + c0 + tx] = (_Float16)(rem - (float)h);
            }
        }
        qt[tx][hwl] = qv;
    }
    __syncthreads();
    {
        int hl = t & 31, cl0 = t >> 5;
#pragma unroll
        for (int it = 0; it < 4; ++it) {
            int cl = cl0 + it * 8;
            int hw = h0 + hl;
            if (hw < HWN) {
                size_t off = ((size_t)b * CDIM + c0 + cl) * HWN + hw;
                float qv = qt[cl][hl];
                xout[off] = qv;
                if (reconp) reconp[off] = qv + x1p[off] + x2p[off];
            }
        }
    }
#pragma unroll
    for (int off = 32; off; off >>= 1) lsum += __shfl_down(lsum, off);
    int lane = t & 63, w = t >> 6;
    if (lane == 0) wsum[w] = lsum;
    __syncthreads();
    if (t == 0) atomicAdd(lacc, wsum[0] + wsum[1] + wsum[2] + wsum[3]);
}

__global__ void finalize_losses(const float* __restrict__ lacc, float* __restrict__ out) {
    int t = threadIdx.x;
    if (t < 3) out[t] = 2.0f * lacc[t] / (float)ETOT;
}

// ------------------------------------------------------------------- launch

extern "C" void kernel_launch(void* const* d_in, const int* in_sizes, int n_in,
                              void* d_out, int out_size, void* d_ws, size_t ws_size,
                              hipStream_t stream) {
    (void)in_sizes; (void)n_in; (void)out_size; (void)ws_size;
    const float* head = (const float*)d_in[0];
    const float* cbs[3] = {(const float*)d_in[1], (const float*)d_in[2], (const float*)d_in[3]};
    float* out = (float*)d_out;
    char* ws = (char*)d_ws;

    size_t o_f = 0;
    size_t o_fs   = o_f   + ETOT * 4;
    size_t o_cs   = o_fs  + (size_t)NR * 1024 * 2;
    size_t o_part = o_cs  + (size_t)KC * 1024 * 2;
    size_t o_idx  = o_part + (size_t)NSTRIP * NR * 16;
    size_t o_cn   = o_idx + (size_t)NR * 4;
    size_t o_la   = o_cn  + (size_t)KC * 4;      // total ~58.85 MB (proven fits, R6)

    float*     f     = (float*)(ws + o_f);
    _Float16*  fs    = (_Float16*)(ws + o_fs);
    _Float16*  cspl  = (_Float16*)(ws + o_cs);
    float4*    part  = (float4*)(ws + o_part);
    int*       idx   = (int*)(ws + o_idx);
    float*     cnorm = (float*)(ws + o_cn);
    float*     lacc  = (float*)(ws + o_la);

    zero_acc<<<1, 64, 0, stream>>>(lacc);
    transpose_head_split<<<dim3(25, 16, 16), 256, 0, stream>>>(head, f, fs);
    for (int s = 0; s < 3; ++s) {
        split_code_norm<<<dim3(KC * 64 / 256), 256, 0, stream>>>(cbs[s], cspl, cnorm);
        argmin_fast<<<dim3(NSTRIP, 49), 512, 0, stream>>>(fs, cspl, cnorm, part);
        combine_fix<<<dim3((NR + 255) / 256), 256, 0, stream>>>(part, f, cbs[s], idx);
        float* xout   = out + (size_t)s * ETOT;
        float* reconp = (s == 2) ? out + 3 * ETOT + 3 : nullptr;
        _Float16* fsout = (s < 2) ? fs : nullptr;
        vq_update<<<dim3(25, 16, 16), 256, 0, stream>>>(f, cbs[s], idx, xout,
                                                        out, out + ETOT, reconp,
                                                        fsout, lacc + s);
    }
    finalize_losses<<<1, 64, 0, stream>>>(lacc, out + 3 * ETOT);
}